// Round 7
// baseline (215.343 us; speedup 1.0000x reference)
//
#include <hip/hip_runtime.h>

#define N_NODES 50000
#define N_EDGES 800000
#define NB 196                 // buckets of 256 nodes: ceil(50000/256)
#define PBLOCKS 128            // partition blocks
#define CHUNK 6250             // N_EDGES / PBLOCKS (exact)
#define SCAN_N (NB * PBLOCKS)  // 25088

typedef unsigned short ushort_t;

__device__ __forceinline__ float bf2f(ushort_t u) {
    return __uint_as_float(((unsigned int)u) << 16);
}
__device__ __forceinline__ ushort_t f2bf(float f) {   // round-to-nearest-even
    unsigned int x = __float_as_uint(f);
    return (ushort_t)((x + 0x7fffu + ((x >> 16) & 1u)) >> 16);
}

// ---------------- CSR build: atomic-free radix partition ----------------

__global__ __launch_bounds__(256)
void part_count(const int* __restrict__ dst, int* __restrict__ blocktot) {
    __shared__ int hist[NB];
    for (int i = threadIdx.x; i < NB; i += 256) hist[i] = 0;
    __syncthreads();
    const int e0 = blockIdx.x * CHUNK;
    const int e1 = e0 + CHUNK;
    for (int e = e0 + (int)threadIdx.x; e < e1; e += 256)
        atomicAdd(&hist[dst[e] >> 8], 1);
    __syncthreads();
    for (int i = threadIdx.x; i < NB; i += 256)
        blocktot[i * PBLOCKS + blockIdx.x] = hist[i];
}

__global__ __launch_bounds__(1024)
void part_scan(const int* __restrict__ blocktot, int* __restrict__ blockstart) {
    __shared__ int psum[1024];
    constexpr int PER = (SCAN_N + 1023) / 1024;   // 25
    const int t = threadIdx.x;
    const int base = t * PER;
    int local[PER];
    int s = 0;
#pragma unroll
    for (int i = 0; i < PER; ++i) {
        int idx = base + i;
        int v = (idx < SCAN_N) ? blocktot[idx] : 0;
        local[i] = s;
        s += v;
    }
    psum[t] = s;
    __syncthreads();
    for (int off = 1; off < 1024; off <<= 1) {
        int add = (t >= off) ? psum[t - off] : 0;
        __syncthreads();
        psum[t] += add;
        __syncthreads();
    }
    const int tbase = psum[t] - s;   // exclusive prefix of this thread
#pragma unroll
    for (int i = 0; i < PER; ++i) {
        int idx = base + i;
        if (idx < SCAN_N) blockstart[idx] = tbase + local[i];
    }
    if (t == 1023) blockstart[SCAN_N] = psum[1023];   // == N_EDGES
}

__global__ __launch_bounds__(256)
void part_write(const int* __restrict__ src, const int* __restrict__ dst,
                const int* __restrict__ blockstart, unsigned int* __restrict__ brec) {
    __shared__ int cur[NB];
    for (int i = threadIdx.x; i < NB; i += 256)
        cur[i] = blockstart[i * PBLOCKS + blockIdx.x];
    __syncthreads();
    const int e0 = blockIdx.x * CHUNK;
    const int e1 = e0 + CHUNK;
    for (int e = e0 + (int)threadIdx.x; e < e1; e += 256) {
        int d = dst[e];
        int s = src[e];
        int pos = atomicAdd(&cur[d >> 8], 1);
        brec[pos] = ((unsigned int)(d & 255) << 16) | (unsigned int)s;
    }
}

__global__ __launch_bounds__(256)
void bucket_fill(const int* __restrict__ blockstart,
                 const unsigned int* __restrict__ brec,
                 int* __restrict__ csr_src, int* __restrict__ row_ptr) {
    __shared__ int cnt[256];
    __shared__ int cur[256];
    const int b = blockIdx.x;
    const int node0 = b * 256;
    const int w0 = blockstart[b * PBLOCKS];
    const int w1 = blockstart[(b + 1) * PBLOCKS];
    const int t = threadIdx.x;
    cnt[t] = 0;
    __syncthreads();
    for (int i = w0 + t; i < w1; i += 256)
        atomicAdd(&cnt[brec[i] >> 16], 1);
    __syncthreads();
    const int v = cnt[t];
    cur[t] = v;
    __syncthreads();
    for (int off = 1; off < 256; off <<= 1) {
        int add = (t >= off) ? cur[t - off] : 0;
        __syncthreads();
        cur[t] += add;
        __syncthreads();
    }
    const int excl = cur[t] - v;
    const int node = node0 + t;
    if (node <= N_NODES) row_ptr[node] = w0 + excl;   // includes sentinel at node==N
    __syncthreads();
    cur[t] = w0 + excl;
    __syncthreads();
    for (int i = w0 + t; i < w1; i += 256) {
        unsigned int r = brec[i];
        int pos = atomicAdd(&cur[r >> 16], 1);
        csr_src[pos] = (int)(r & 0xffffu);
    }
}

// ---------------- Layer-1 GEMM: [Tself1|Tn1] = x @ [Ws1|Wn1] ----------------
__global__ __launch_bounds__(256)
void gemm_cat128(const float* __restrict__ A,
                 const float* __restrict__ B1,   // [64, 64]
                 const float* __restrict__ B2,   // [64, 64]
                 float* __restrict__ Cself,      // [N, 64] fp32
                 ushort_t* __restrict__ Cn) {    // [N, 64] bf16
    __shared__ float As[64][68];
    __shared__ float Bs[64][128];

    for (int i = threadIdx.x; i < 64 * 64; i += 256) {
        int k = i >> 6, j = i & 63;
        Bs[k][j]      = B1[i];
        Bs[k][j + 64] = B2[i];
    }
    const int m0 = blockIdx.x * 64;
    {
        int mloc = threadIdx.x >> 4;
        int k4   = (threadIdx.x & 15) * 4;
#pragma unroll
        for (int it = 0; it < 4; ++it) {
            int m  = mloc + it * 16;
            int gm = m0 + m;
            float4 a = (gm < N_NODES) ? *(const float4*)&A[(size_t)gm * 64 + k4]
                                      : make_float4(0.f, 0.f, 0.f, 0.f);
            As[k4 + 0][m] = a.x; As[k4 + 1][m] = a.y;
            As[k4 + 2][m] = a.z; As[k4 + 3][m] = a.w;
        }
    }
    __syncthreads();

    const int tm  = ((threadIdx.x >> 4) & 3) * 4 + (threadIdx.x >> 6) * 16;  // 0..60
    const int tn4 = (threadIdx.x & 15) * 4;                                   // 0..60

    float acc[4][2][4];
#pragma unroll
    for (int mi = 0; mi < 4; ++mi)
#pragma unroll
        for (int hh = 0; hh < 2; ++hh)
#pragma unroll
            for (int ni = 0; ni < 4; ++ni) acc[mi][hh][ni] = 0.f;

#pragma unroll 8
    for (int k = 0; k < 64; ++k) {
        float4 a = *(const float4*)&As[k][tm];
        float4 b0 = *(const float4*)&Bs[k][tn4];
        float4 b1v = *(const float4*)&Bs[k][tn4 + 64];
        const float am[4] = {a.x, a.y, a.z, a.w};
#pragma unroll
        for (int mi = 0; mi < 4; ++mi) {
            acc[mi][0][0] += am[mi] * b0.x; acc[mi][0][1] += am[mi] * b0.y;
            acc[mi][0][2] += am[mi] * b0.z; acc[mi][0][3] += am[mi] * b0.w;
            acc[mi][1][0] += am[mi] * b1v.x; acc[mi][1][1] += am[mi] * b1v.y;
            acc[mi][1][2] += am[mi] * b1v.z; acc[mi][1][3] += am[mi] * b1v.w;
        }
    }

#pragma unroll
    for (int mi = 0; mi < 4; ++mi) {
        int gm = m0 + tm + mi;
        if (gm < N_NODES) {
            *(float4*)&Cself[(size_t)gm * 64 + tn4] = *(float4*)&acc[mi][0][0];
            ushort4 u;
            u.x = f2bf(acc[mi][1][0]); u.y = f2bf(acc[mi][1][1]);
            u.z = f2bf(acc[mi][1][2]); u.w = f2bf(acc[mi][1][3]);
            *(ushort4*)&Cn[(size_t)gm * 64 + tn4] = u;
        }
    }
}

// ---------------- Fused: layer-1 gather epilogue + layer-2 GEMM ----------------
// Per 64-node tile: h[v] = relu(Tself1[v] + mean Tn1[nbr] + b1) -> LDS (transposed)
// then [Tself2|Tn2] = h_tile @ [Ws2|Wn2].
__global__ __launch_bounds__(256)
void gather1_gemm2(const float* __restrict__ Tself1, const ushort_t* __restrict__ Tn1,
                   const int* __restrict__ row_ptr, const int* __restrict__ csr_src,
                   const float* __restrict__ b1,
                   const float* __restrict__ Ws2, const float* __restrict__ Wn2,
                   float* __restrict__ Tself2,     // [N,32] fp32
                   ushort_t* __restrict__ Tn2) {   // [N,32] bf16
    __shared__ float hs[64][68];    // transposed h tile: hs[k][m]
    __shared__ float Bs[64][64];    // [Ws2|Wn2]

    for (int i = threadIdx.x; i < 64 * 32; i += 256) {
        int k = i >> 5, j = i & 31;
        Bs[k][j]      = Ws2[i];
        Bs[k][j + 32] = Wn2[i];
    }

    const int m0   = blockIdx.x * 64;
    const int wave = threadIdx.x >> 6;
    const int lane = threadIdx.x & 63;
    const int r = lane >> 4;        // 0..3  (row group)
    const int c = lane & 15;        // 0..15 (float4 column)
    const float4 b1c = *(const float4*)&b1[c * 4];

    // gather 16 nodes per wave
    for (int i = 0; i < 16; ++i) {
        const int v = m0 + wave * 16 + i;
        if (v < N_NODES) {
            const int start = row_ptr[v];
            const int cnt   = row_ptr[v + 1] - start;
            float a0 = 0.f, a1 = 0.f, a2 = 0.f, a3 = 0.f;
            int t = r;
            for (; t + 4 < cnt; t += 8) {
                int s0 = csr_src[start + t];
                int s1 = csr_src[start + t + 4];
                ushort4 u0 = *(const ushort4*)&Tn1[(size_t)s0 * 64 + c * 4];
                ushort4 u1 = *(const ushort4*)&Tn1[(size_t)s1 * 64 + c * 4];
                a0 += bf2f(u0.x) + bf2f(u1.x);
                a1 += bf2f(u0.y) + bf2f(u1.y);
                a2 += bf2f(u0.z) + bf2f(u1.z);
                a3 += bf2f(u0.w) + bf2f(u1.w);
            }
            if (t < cnt) {
                int s = csr_src[start + t];
                ushort4 u = *(const ushort4*)&Tn1[(size_t)s * 64 + c * 4];
                a0 += bf2f(u.x); a1 += bf2f(u.y); a2 += bf2f(u.z); a3 += bf2f(u.w);
            }
            a0 += __shfl_xor(a0, 16); a0 += __shfl_xor(a0, 32);
            a1 += __shfl_xor(a1, 16); a1 += __shfl_xor(a1, 32);
            a2 += __shfl_xor(a2, 16); a2 += __shfl_xor(a2, 32);
            a3 += __shfl_xor(a3, 16); a3 += __shfl_xor(a3, 32);
            if (r == 0) {
                const float inv = 1.0f / (float)max(cnt, 1);
                float4 self = *(const float4*)&Tself1[(size_t)v * 64 + c * 4];
                const int m = wave * 16 + i;
                hs[c * 4 + 0][m] = fmaxf(self.x + a0 * inv + b1c.x, 0.f);
                hs[c * 4 + 1][m] = fmaxf(self.y + a1 * inv + b1c.y, 0.f);
                hs[c * 4 + 2][m] = fmaxf(self.z + a2 * inv + b1c.z, 0.f);
                hs[c * 4 + 3][m] = fmaxf(self.w + a3 * inv + b1c.w, 0.f);
            }
        } else if (r == 0) {
            const int m = wave * 16 + i;
            hs[c * 4 + 0][m] = 0.f; hs[c * 4 + 1][m] = 0.f;
            hs[c * 4 + 2][m] = 0.f; hs[c * 4 + 3][m] = 0.f;
        }
    }
    __syncthreads();

    // GEMM: 64 nodes x 64 cols; thread tile 4m x 4n
    const int tm  = ((threadIdx.x >> 4) & 3) * 4 + (threadIdx.x >> 6) * 16;  // 0..60
    const int tn4 = (threadIdx.x & 15) * 4;                                   // 0..60

    float acc[4][4];
#pragma unroll
    for (int mi = 0; mi < 4; ++mi)
#pragma unroll
        for (int ni = 0; ni < 4; ++ni) acc[mi][ni] = 0.f;

#pragma unroll 8
    for (int k = 0; k < 64; ++k) {
        float4 a = *(const float4*)&hs[k][tm];
        float4 b = *(const float4*)&Bs[k][tn4];
        const float am[4] = {a.x, a.y, a.z, a.w};
#pragma unroll
        for (int mi = 0; mi < 4; ++mi) {
            acc[mi][0] += am[mi] * b.x; acc[mi][1] += am[mi] * b.y;
            acc[mi][2] += am[mi] * b.z; acc[mi][3] += am[mi] * b.w;
        }
    }

#pragma unroll
    for (int mi = 0; mi < 4; ++mi) {
        int gm = m0 + tm + mi;
        if (gm < N_NODES) {
            if (tn4 < 32) {
                *(float4*)&Tself2[(size_t)gm * 32 + tn4] = *(float4*)&acc[mi][0];
            } else {
                ushort4 u;
                u.x = f2bf(acc[mi][0]); u.y = f2bf(acc[mi][1]);
                u.z = f2bf(acc[mi][2]); u.w = f2bf(acc[mi][3]);
                *(ushort4*)&Tn2[(size_t)gm * 32 + (tn4 - 32)] = u;
            }
        }
    }
}

// ---------------- Final gather mean + epilogue (layer 2) ----------------
__global__ __launch_bounds__(256)
void gather_final(const float* __restrict__ Tself, const ushort_t* __restrict__ Tn,
                  const int* __restrict__ row_ptr, const int* __restrict__ csr_src,
                  const float* __restrict__ bias, float* __restrict__ out) {
    constexpr int LPR = 8;   // 32 cols / 4
    constexpr int R   = 8;
    int v = (blockIdx.x * blockDim.x + threadIdx.x) >> 6;   // node id
    int lane = threadIdx.x & 63;
    int r = lane / LPR;
    int c = lane % LPR;
    if (v >= N_NODES) return;
    int start = row_ptr[v];
    int cnt   = row_ptr[v + 1] - start;

    float a0 = 0.f, a1 = 0.f, a2 = 0.f, a3 = 0.f;
    int t = r;
    for (; t + R < cnt; t += 2 * R) {
        int s0 = csr_src[start + t];
        int s1 = csr_src[start + t + R];
        ushort4 u0 = *(const ushort4*)&Tn[(size_t)s0 * 32 + c * 4];
        ushort4 u1 = *(const ushort4*)&Tn[(size_t)s1 * 32 + c * 4];
        a0 += bf2f(u0.x) + bf2f(u1.x);
        a1 += bf2f(u0.y) + bf2f(u1.y);
        a2 += bf2f(u0.z) + bf2f(u1.z);
        a3 += bf2f(u0.w) + bf2f(u1.w);
    }
    if (t < cnt) {
        int s = csr_src[start + t];
        ushort4 u = *(const ushort4*)&Tn[(size_t)s * 32 + c * 4];
        a0 += bf2f(u.x); a1 += bf2f(u.y); a2 += bf2f(u.z); a3 += bf2f(u.w);
    }
#pragma unroll
    for (int off = LPR; off < 64; off <<= 1) {
        a0 += __shfl_xor(a0, off);
        a1 += __shfl_xor(a1, off);
        a2 += __shfl_xor(a2, off);
        a3 += __shfl_xor(a3, off);
    }
    if (r == 0) {
        float inv = 1.0f / (float)max(cnt, 1);
        float4 self = *(const float4*)&Tself[(size_t)v * 32 + c * 4];
        float4 b4   = *(const float4*)&bias[c * 4];
        float4 o;
        o.x = self.x + a0 * inv + b4.x;
        o.y = self.y + a1 * inv + b4.y;
        o.z = self.z + a2 * inv + b4.z;
        o.w = self.w + a3 * inv + b4.w;
        *(float4*)&out[(size_t)v * 32 + c * 4] = o;
    }
}

extern "C" void kernel_launch(void* const* d_in, const int* in_sizes, int n_in,
                              void* d_out, int out_size, void* d_ws, size_t ws_size,
                              hipStream_t stream) {
    const float* features = (const float*)d_in[0];
    const float* W_self1  = (const float*)d_in[1];
    const float* W_neigh1 = (const float*)d_in[2];
    const float* b1       = (const float*)d_in[3];
    const float* W_self2  = (const float*)d_in[4];
    const float* W_neigh2 = (const float*)d_in[5];
    const float* b2       = (const float*)d_in[6];
    const int*   src      = (const int*)d_in[7];
    const int*   dst      = (const int*)d_in[8];
    float*       out      = (float*)d_out;

    // Workspace:
    //   Tself1 : N*64 f32 (12.8 MB)   Tn1 : N*64 bf16 (6.4 MB)
    //   Tself2 : N*32 f32 (6.4 MB)    Tn2 : N*32 bf16 (3.2 MB)
    //   row_ptr: N+1; csr_src: E; brec: E; blocktot/blockstart: SCAN_N(+1)
    float*    Tself1 = (float*)d_ws;
    ushort_t* Tn1    = (ushort_t*)(Tself1 + (size_t)N_NODES * 64);
    float*    Tself2 = (float*)(Tn1 + (size_t)N_NODES * 64);
    ushort_t* Tn2    = (ushort_t*)(Tself2 + (size_t)N_NODES * 32);
    int* row_ptr     = (int*)(Tn2 + (size_t)N_NODES * 32);
    int* csr_src     = row_ptr + (N_NODES + 1);
    unsigned int* brec = (unsigned int*)(csr_src + N_EDGES);
    int* blocktot    = (int*)(brec + N_EDGES);
    int* blockstart  = blocktot + SCAN_N;

    // ---- CSR build (by dst), atomic-free partition ----
    part_count<<<PBLOCKS, 256, 0, stream>>>(dst, blocktot);
    part_scan<<<1, 1024, 0, stream>>>(blocktot, blockstart);
    part_write<<<PBLOCKS, 256, 0, stream>>>(src, dst, blockstart, brec);
    bucket_fill<<<NB, 256, 0, stream>>>(blockstart, brec, csr_src, row_ptr);

    const int tile_blocks   = (N_NODES + 63) / 64;   // 782
    const int gather_blocks = (N_NODES + 3) / 4;     // 12500

    // ---- Layer 1 GEMM ----
    gemm_cat128<<<tile_blocks, 256, 0, stream>>>(features, W_self1, W_neigh1, Tself1, Tn1);
    // ---- Fused: layer-1 gather epilogue + layer-2 GEMM ----
    gather1_gemm2<<<tile_blocks, 256, 0, stream>>>(
        Tself1, Tn1, row_ptr, csr_src, b1, W_self2, W_neigh2, Tself2, Tn2);
    // ---- Final gather + epilogue ----
    gather_final<<<gather_blocks, 256, 0, stream>>>(
        Tself2, Tn2, row_ptr, csr_src, b2, out);
}

// Round 8
// 199.396 us; speedup vs baseline: 1.0800x; 1.0800x over previous
//
#include <hip/hip_runtime.h>

#define N_NODES 50000
#define N_EDGES 800000
#define NB 196                 // buckets of 256 nodes: ceil(50000/256)
#define PBLOCKS 128            // partition blocks
#define CHUNK 6250             // N_EDGES / PBLOCKS (exact)
#define SCAN_N (NB * PBLOCKS)  // 25088

typedef unsigned short ushort_t;

__device__ __forceinline__ float bf2f(ushort_t u) {
    return __uint_as_float(((unsigned int)u) << 16);
}
__device__ __forceinline__ ushort_t f2bf(float f) {   // round-to-nearest-even
    unsigned int x = __float_as_uint(f);
    return (ushort_t)((x + 0x7fffu + ((x >> 16) & 1u)) >> 16);
}

// ---------------- CSR build: atomic-free radix partition ----------------

__global__ __launch_bounds__(256)
void part_count(const int* __restrict__ dst, int* __restrict__ blocktot) {
    __shared__ int hist[NB];
    for (int i = threadIdx.x; i < NB; i += 256) hist[i] = 0;
    __syncthreads();
    const int e0 = blockIdx.x * CHUNK;
    const int e1 = e0 + CHUNK;
    for (int e = e0 + (int)threadIdx.x; e < e1; e += 256)
        atomicAdd(&hist[dst[e] >> 8], 1);
    __syncthreads();
    for (int i = threadIdx.x; i < NB; i += 256)
        blocktot[i * PBLOCKS + blockIdx.x] = hist[i];
}

__global__ __launch_bounds__(1024)
void part_scan(const int* __restrict__ blocktot, int* __restrict__ blockstart) {
    __shared__ int psum[1024];
    constexpr int PER = (SCAN_N + 1023) / 1024;   // 25
    const int t = threadIdx.x;
    const int base = t * PER;
    int local[PER];
    int s = 0;
#pragma unroll
    for (int i = 0; i < PER; ++i) {
        int idx = base + i;
        int v = (idx < SCAN_N) ? blocktot[idx] : 0;
        local[i] = s;
        s += v;
    }
    psum[t] = s;
    __syncthreads();
    for (int off = 1; off < 1024; off <<= 1) {
        int add = (t >= off) ? psum[t - off] : 0;
        __syncthreads();
        psum[t] += add;
        __syncthreads();
    }
    const int tbase = psum[t] - s;   // exclusive prefix of this thread
#pragma unroll
    for (int i = 0; i < PER; ++i) {
        int idx = base + i;
        if (idx < SCAN_N) blockstart[idx] = tbase + local[i];
    }
    if (t == 1023) blockstart[SCAN_N] = psum[1023];   // == N_EDGES
}

__global__ __launch_bounds__(256)
void part_write(const int* __restrict__ src, const int* __restrict__ dst,
                const int* __restrict__ blockstart, unsigned int* __restrict__ brec) {
    __shared__ int cur[NB];
    for (int i = threadIdx.x; i < NB; i += 256)
        cur[i] = blockstart[i * PBLOCKS + blockIdx.x];
    __syncthreads();
    const int e0 = blockIdx.x * CHUNK;
    const int e1 = e0 + CHUNK;
    for (int e = e0 + (int)threadIdx.x; e < e1; e += 256) {
        int d = dst[e];
        int s = src[e];
        int pos = atomicAdd(&cur[d >> 8], 1);
        brec[pos] = ((unsigned int)(d & 255) << 16) | (unsigned int)s;
    }
}

__global__ __launch_bounds__(256)
void bucket_fill(const int* __restrict__ blockstart,
                 const unsigned int* __restrict__ brec,
                 int* __restrict__ csr_src, int* __restrict__ row_ptr) {
    __shared__ int cnt[256];
    __shared__ int cur[256];
    const int b = blockIdx.x;
    const int node0 = b * 256;
    const int w0 = blockstart[b * PBLOCKS];
    const int w1 = blockstart[(b + 1) * PBLOCKS];
    const int t = threadIdx.x;
    cnt[t] = 0;
    __syncthreads();
    for (int i = w0 + t; i < w1; i += 256)
        atomicAdd(&cnt[brec[i] >> 16], 1);
    __syncthreads();
    const int v = cnt[t];
    cur[t] = v;
    __syncthreads();
    for (int off = 1; off < 256; off <<= 1) {
        int add = (t >= off) ? cur[t - off] : 0;
        __syncthreads();
        cur[t] += add;
        __syncthreads();
    }
    const int excl = cur[t] - v;
    const int node = node0 + t;
    if (node <= N_NODES) row_ptr[node] = w0 + excl;   // includes sentinel at node==N
    __syncthreads();
    cur[t] = w0 + excl;
    __syncthreads();
    for (int i = w0 + t; i < w1; i += 256) {
        unsigned int r = brec[i];
        int pos = atomicAdd(&cur[r >> 16], 1);
        csr_src[pos] = (int)(r & 0xffffu);
    }
}

// ---------------- Register-tiled fp32 GEMM: [Cself|Cn] = A[N,64] @ [B1|B2] ----------------
// Both halves stored bf16 (RNE): self read once sequentially, neighbor gathered.
template <int F>
__global__ __launch_bounds__(256)
void gemm_cat(const float* __restrict__ A,
              const float* __restrict__ B1,   // [64, H]
              const float* __restrict__ B2,   // [64, H]
              ushort_t* __restrict__ Cself,   // [N, H] bf16
              ushort_t* __restrict__ Cn) {    // [N, H] bf16
    constexpr int H = F / 2;
    constexpr int HALVES = F / 64;          // 1 or 2
    __shared__ float As[64][68];            // transposed A tile, padded
    __shared__ float Bs[64][F];

    for (int i = threadIdx.x; i < 64 * H; i += 256) {
        int k = i / H, j = i % H;
        Bs[k][j]     = B1[i];
        Bs[k][j + H] = B2[i];
    }
    const int m0 = blockIdx.x * 64;
    {
        int mloc = threadIdx.x >> 4;          // 0..15
        int k4   = (threadIdx.x & 15) * 4;    // 0..60
#pragma unroll
        for (int it = 0; it < 4; ++it) {
            int m  = mloc + it * 16;
            int gm = m0 + m;
            float4 a = (gm < N_NODES) ? *(const float4*)&A[(size_t)gm * 64 + k4]
                                      : make_float4(0.f, 0.f, 0.f, 0.f);
            As[k4 + 0][m] = a.x; As[k4 + 1][m] = a.y;
            As[k4 + 2][m] = a.z; As[k4 + 3][m] = a.w;
        }
    }
    __syncthreads();

    const int tm  = ((threadIdx.x >> 4) & 3) * 4 + (threadIdx.x >> 6) * 16;  // 0..60
    const int tn4 = (threadIdx.x & 15) * 4;                                   // 0..60

    float acc[4][HALVES][4];
#pragma unroll
    for (int mi = 0; mi < 4; ++mi)
#pragma unroll
        for (int hh = 0; hh < HALVES; ++hh)
#pragma unroll
            for (int ni = 0; ni < 4; ++ni) acc[mi][hh][ni] = 0.f;

#pragma unroll 8
    for (int k = 0; k < 64; ++k) {
        float4 a = *(const float4*)&As[k][tm];
        float4 b[HALVES];
#pragma unroll
        for (int hh = 0; hh < HALVES; ++hh)
            b[hh] = *(const float4*)&Bs[k][tn4 + hh * 64];
        const float am[4] = {a.x, a.y, a.z, a.w};
#pragma unroll
        for (int mi = 0; mi < 4; ++mi) {
#pragma unroll
            for (int hh = 0; hh < HALVES; ++hh) {
                acc[mi][hh][0] += am[mi] * b[hh].x;
                acc[mi][hh][1] += am[mi] * b[hh].y;
                acc[mi][hh][2] += am[mi] * b[hh].z;
                acc[mi][hh][3] += am[mi] * b[hh].w;
            }
        }
    }

#pragma unroll
    for (int mi = 0; mi < 4; ++mi) {
        int gm = m0 + tm + mi;
        if (gm < N_NODES) {
#pragma unroll
            for (int hh = 0; hh < HALVES; ++hh) {
                int col = tn4 + hh * 64;
                ushort4 u;
                u.x = f2bf(acc[mi][hh][0]);
                u.y = f2bf(acc[mi][hh][1]);
                u.z = f2bf(acc[mi][hh][2]);
                u.w = f2bf(acc[mi][hh][3]);
                if (col < H) {
                    *(ushort4*)&Cself[(size_t)gm * H + col] = u;
                } else {
                    *(ushort4*)&Cn[(size_t)gm * H + (col - H)] = u;
                }
            }
        }
    }
}

// ---------------- Gather mean (bf16 tables) + fused epilogue ----------------
// out[v] = act( Cself[v] + mean_{u in N(v)} Cn[u] + bias )
// One wave per node; LPR = F/4 lanes per row (ushort4 = 8B each); R = 64/LPR
// rows in flight per tier; 4-deep unroll = up to 4*R rows outstanding.
template <int F, bool RELU>
__global__ __launch_bounds__(256)
void gather_epilogue(const ushort_t* __restrict__ Tself,
                     const ushort_t* __restrict__ Tn,
                     const int* __restrict__ row_ptr,
                     const int* __restrict__ csr_src, const float* __restrict__ bias,
                     float* __restrict__ out) {
    constexpr int LPR = F / 4;
    constexpr int R   = 64 / LPR;
    int v = (blockIdx.x * blockDim.x + threadIdx.x) >> 6;   // node id
    int lane = threadIdx.x & 63;
    int r = lane / LPR;
    int c = lane % LPR;
    if (v >= N_NODES) return;
    int start = row_ptr[v];
    int cnt   = row_ptr[v + 1] - start;

    float a0 = 0.f, a1 = 0.f, a2 = 0.f, a3 = 0.f;
    int t = r;
    for (; t + 3 * R < cnt; t += 4 * R) {   // 4-deep: 4*R rows in flight per wave
        int s0 = csr_src[start + t];
        int s1 = csr_src[start + t + R];
        int s2 = csr_src[start + t + 2 * R];
        int s3 = csr_src[start + t + 3 * R];
        ushort4 u0 = *(const ushort4*)&Tn[(size_t)s0 * F + c * 4];
        ushort4 u1 = *(const ushort4*)&Tn[(size_t)s1 * F + c * 4];
        ushort4 u2 = *(const ushort4*)&Tn[(size_t)s2 * F + c * 4];
        ushort4 u3 = *(const ushort4*)&Tn[(size_t)s3 * F + c * 4];
        a0 += bf2f(u0.x) + bf2f(u1.x) + bf2f(u2.x) + bf2f(u3.x);
        a1 += bf2f(u0.y) + bf2f(u1.y) + bf2f(u2.y) + bf2f(u3.y);
        a2 += bf2f(u0.z) + bf2f(u1.z) + bf2f(u2.z) + bf2f(u3.z);
        a3 += bf2f(u0.w) + bf2f(u1.w) + bf2f(u2.w) + bf2f(u3.w);
    }
    for (; t + R < cnt; t += 2 * R) {
        int s0 = csr_src[start + t];
        int s1 = csr_src[start + t + R];
        ushort4 u0 = *(const ushort4*)&Tn[(size_t)s0 * F + c * 4];
        ushort4 u1 = *(const ushort4*)&Tn[(size_t)s1 * F + c * 4];
        a0 += bf2f(u0.x) + bf2f(u1.x);
        a1 += bf2f(u0.y) + bf2f(u1.y);
        a2 += bf2f(u0.z) + bf2f(u1.z);
        a3 += bf2f(u0.w) + bf2f(u1.w);
    }
    if (t < cnt) {
        int s = csr_src[start + t];
        ushort4 u = *(const ushort4*)&Tn[(size_t)s * F + c * 4];
        a0 += bf2f(u.x); a1 += bf2f(u.y); a2 += bf2f(u.z); a3 += bf2f(u.w);
    }
#pragma unroll
    for (int off = LPR; off < 64; off <<= 1) {
        a0 += __shfl_xor(a0, off);
        a1 += __shfl_xor(a1, off);
        a2 += __shfl_xor(a2, off);
        a3 += __shfl_xor(a3, off);
    }
    if (r == 0) {
        float inv = 1.0f / (float)max(cnt, 1);
        ushort4 su = *(const ushort4*)&Tself[(size_t)v * F + c * 4];
        float4 b4  = *(const float4*)&bias[c * 4];
        float4 o;
        o.x = bf2f(su.x) + a0 * inv + b4.x;
        o.y = bf2f(su.y) + a1 * inv + b4.y;
        o.z = bf2f(su.z) + a2 * inv + b4.z;
        o.w = bf2f(su.w) + a3 * inv + b4.w;
        if (RELU) {
            o.x = fmaxf(o.x, 0.f); o.y = fmaxf(o.y, 0.f);
            o.z = fmaxf(o.z, 0.f); o.w = fmaxf(o.w, 0.f);
        }
        *(float4*)&out[(size_t)v * F + c * 4] = o;
    }
}

extern "C" void kernel_launch(void* const* d_in, const int* in_sizes, int n_in,
                              void* d_out, int out_size, void* d_ws, size_t ws_size,
                              hipStream_t stream) {
    const float* features = (const float*)d_in[0];
    const float* W_self1  = (const float*)d_in[1];
    const float* W_neigh1 = (const float*)d_in[2];
    const float* b1       = (const float*)d_in[3];
    const float* W_self2  = (const float*)d_in[4];
    const float* W_neigh2 = (const float*)d_in[5];
    const float* b2       = (const float*)d_in[6];
    const int*   src      = (const int*)d_in[7];
    const int*   dst      = (const int*)d_in[8];
    float*       out      = (float*)d_out;

    // Workspace:
    //   Tself1 : N*64 bf16 (6.4 MB)  -- layer-1 self (reused as Tself2+Tn2, N*32 each)
    //   Tn1    : N*64 bf16 (6.4 MB)  -- layer-1 neighbor
    //   h      : N*64 f32 (12.8 MB)
    //   row_ptr: N+1; csr_src: E; brec: E; blocktot/blockstart: SCAN_N(+1)
    ushort_t* Tself1 = (ushort_t*)d_ws;
    ushort_t* Tn1    = Tself1 + (size_t)N_NODES * 64;
    float*    h      = (float*)(Tn1 + (size_t)N_NODES * 64);
    int* row_ptr     = (int*)(h + (size_t)N_NODES * 64);
    int* csr_src     = row_ptr + (N_NODES + 1);
    unsigned int* brec = (unsigned int*)(csr_src + N_EDGES);
    int* blocktot    = (int*)(brec + N_EDGES);
    int* blockstart  = blocktot + SCAN_N;

    // Layer-2 tables reuse Tself1's allocation (dead after layer-1 gather).
    ushort_t* Tself2 = Tself1;                       // N*32
    ushort_t* Tn2    = Tself1 + (size_t)N_NODES * 32;

    // ---- CSR build (by dst), atomic-free partition ----
    part_count<<<PBLOCKS, 256, 0, stream>>>(dst, blocktot);
    part_scan<<<1, 1024, 0, stream>>>(blocktot, blockstart);
    part_write<<<PBLOCKS, 256, 0, stream>>>(src, dst, blockstart, brec);
    bucket_fill<<<NB, 256, 0, stream>>>(blockstart, brec, csr_src, row_ptr);

    const int tile_blocks   = (N_NODES + 63) / 64;   // 782
    const int gather_blocks = (N_NODES + 3) / 4;     // 12500 (4 waves/block)

    // ---- Layer 1 ----
    gemm_cat<128><<<tile_blocks, 256, 0, stream>>>(features, W_self1, W_neigh1, Tself1, Tn1);
    gather_epilogue<64, true><<<gather_blocks, 256, 0, stream>>>(
        Tself1, Tn1, row_ptr, csr_src, b1, h);

    // ---- Layer 2 ----
    gemm_cat<64><<<tile_blocks, 256, 0, stream>>>(h, W_self2, W_neigh2, Tself2, Tn2);
    gather_epilogue<32, false><<<gather_blocks, 256, 0, stream>>>(
        Tself2, Tn2, row_ptr, csr_src, b2, out);
}

// Round 9
// 196.228 us; speedup vs baseline: 1.0974x; 1.0161x over previous
//
#include <hip/hip_runtime.h>

#define N_NODES 50000
#define N_EDGES 800000
#define NB 196                 // buckets of 256 nodes: ceil(50000/256)
#define PBLOCKS 128            // partition blocks
#define CHUNK 6250             // N_EDGES / PBLOCKS (exact)
#define SCAN_N (NB * PBLOCKS)  // 25088
#define GEMM_BLOCKS 782        // ceil(50000/64)

typedef unsigned short ushort_t;

__device__ __forceinline__ float bflo(unsigned int u) {
    return __uint_as_float(u << 16);
}
__device__ __forceinline__ float bfhi(unsigned int u) {
    return __uint_as_float(u & 0xffff0000u);
}
__device__ __forceinline__ ushort_t f2bf(float f) {   // round-to-nearest-even
    unsigned int x = __float_as_uint(f);
    return (ushort_t)((x + 0x7fffu + ((x >> 16) & 1u)) >> 16);
}
__device__ __forceinline__ unsigned int pack_bf(float lo, float hi) {
    return (unsigned int)f2bf(lo) | ((unsigned int)f2bf(hi) << 16);
}

// ---------------- CSR build: atomic-free radix partition ----------------

__global__ __launch_bounds__(1024)
void part_scan(const int* __restrict__ blocktot, int* __restrict__ blockstart) {
    __shared__ int psum[1024];
    constexpr int PER = (SCAN_N + 1023) / 1024;   // 25
    const int t = threadIdx.x;
    const int base = t * PER;
    int local[PER];
    int s = 0;
#pragma unroll
    for (int i = 0; i < PER; ++i) {
        int idx = base + i;
        int v = (idx < SCAN_N) ? blocktot[idx] : 0;
        local[i] = s;
        s += v;
    }
    psum[t] = s;
    __syncthreads();
    for (int off = 1; off < 1024; off <<= 1) {
        int add = (t >= off) ? psum[t - off] : 0;
        __syncthreads();
        psum[t] += add;
        __syncthreads();
    }
    const int tbase = psum[t] - s;   // exclusive prefix of this thread
#pragma unroll
    for (int i = 0; i < PER; ++i) {
        int idx = base + i;
        if (idx < SCAN_N) blockstart[idx] = tbase + local[i];
    }
    if (t == 1023) blockstart[SCAN_N] = psum[1023];   // == N_EDGES
}

__global__ __launch_bounds__(256)
void part_write(const int* __restrict__ src, const int* __restrict__ dst,
                const int* __restrict__ blockstart, unsigned int* __restrict__ brec) {
    __shared__ int cur[NB];
    for (int i = threadIdx.x; i < NB; i += 256)
        cur[i] = blockstart[i * PBLOCKS + blockIdx.x];
    __syncthreads();
    const int e0 = blockIdx.x * CHUNK;
    const int e1 = e0 + CHUNK;
    for (int e = e0 + (int)threadIdx.x; e < e1; e += 256) {
        int d = dst[e];
        int s = src[e];
        int pos = atomicAdd(&cur[d >> 8], 1);
        brec[pos] = ((unsigned int)(d & 255) << 16) | (unsigned int)s;
    }
}

__global__ __launch_bounds__(256)
void bucket_fill(const int* __restrict__ blockstart,
                 const unsigned int* __restrict__ brec,
                 int* __restrict__ csr_src, int* __restrict__ row_ptr) {
    __shared__ int cnt[256];
    __shared__ int cur[256];
    const int b = blockIdx.x;
    const int node0 = b * 256;
    const int w0 = blockstart[b * PBLOCKS];
    const int w1 = blockstart[(b + 1) * PBLOCKS];
    const int t = threadIdx.x;
    cnt[t] = 0;
    __syncthreads();
    for (int i = w0 + t; i < w1; i += 256)
        atomicAdd(&cnt[brec[i] >> 16], 1);
    __syncthreads();
    const int v = cnt[t];
    cur[t] = v;
    __syncthreads();
    for (int off = 1; off < 256; off <<= 1) {
        int add = (t >= off) ? cur[t - off] : 0;
        __syncthreads();
        cur[t] += add;
        __syncthreads();
    }
    const int excl = cur[t] - v;
    const int node = node0 + t;
    if (node <= N_NODES) row_ptr[node] = w0 + excl;   // includes sentinel at node==N
    __syncthreads();
    cur[t] = w0 + excl;
    __syncthreads();
    for (int i = w0 + t; i < w1; i += 256) {
        unsigned int r = brec[i];
        int pos = atomicAdd(&cur[r >> 16], 1);
        csr_src[pos] = (int)(r & 0xffffu);
    }
}

// ---------------- Fused: layer-1 GEMM (782 blocks) + part_count (128 blocks) --------
// Independent work overlapped in one dispatch; per-block uniform branch.
__global__ __launch_bounds__(256)
void gemm128_and_count(const float* __restrict__ A,
                       const float* __restrict__ B1,   // [64,64] Ws1
                       const float* __restrict__ B2,   // [64,64] Wn1
                       ushort_t* __restrict__ Cself,   // [N,64] bf16
                       ushort_t* __restrict__ Cn,      // [N,64] bf16
                       const int* __restrict__ dst,
                       int* __restrict__ blocktot) {
    __shared__ __align__(16) char smem[50176];

    if (blockIdx.x >= GEMM_BLOCKS) {
        // ---- part_count ----
        int* hist = (int*)smem;
        const int pb = blockIdx.x - GEMM_BLOCKS;
        for (int i = threadIdx.x; i < NB; i += 256) hist[i] = 0;
        __syncthreads();
        const int e0 = pb * CHUNK;
        const int e1 = e0 + CHUNK;
        for (int e = e0 + (int)threadIdx.x; e < e1; e += 256)
            atomicAdd(&hist[dst[e] >> 8], 1);
        __syncthreads();
        for (int i = threadIdx.x; i < NB; i += 256)
            blocktot[i * PBLOCKS + pb] = hist[i];
        return;
    }

    // ---- gemm_cat<128> ----
    float (*As)[68]  = (float(*)[68])smem;              // 17408 B
    float (*Bs)[128] = (float(*)[128])(smem + 17408);   // 32768 B

    for (int i = threadIdx.x; i < 64 * 64; i += 256) {
        int k = i >> 6, j = i & 63;
        Bs[k][j]      = B1[i];
        Bs[k][j + 64] = B2[i];
    }
    const int m0 = blockIdx.x * 64;
    {
        int mloc = threadIdx.x >> 4;          // 0..15
        int k4   = (threadIdx.x & 15) * 4;    // 0..60
#pragma unroll
        for (int it = 0; it < 4; ++it) {
            int m  = mloc + it * 16;
            int gm = m0 + m;
            float4 a = (gm < N_NODES) ? *(const float4*)&A[(size_t)gm * 64 + k4]
                                      : make_float4(0.f, 0.f, 0.f, 0.f);
            As[k4 + 0][m] = a.x; As[k4 + 1][m] = a.y;
            As[k4 + 2][m] = a.z; As[k4 + 3][m] = a.w;
        }
    }
    __syncthreads();

    const int tm  = ((threadIdx.x >> 4) & 3) * 4 + (threadIdx.x >> 6) * 16;  // 0..60
    const int tn4 = (threadIdx.x & 15) * 4;                                   // 0..60

    float acc[4][2][4];
#pragma unroll
    for (int mi = 0; mi < 4; ++mi)
#pragma unroll
        for (int hh = 0; hh < 2; ++hh)
#pragma unroll
            for (int ni = 0; ni < 4; ++ni) acc[mi][hh][ni] = 0.f;

#pragma unroll 8
    for (int k = 0; k < 64; ++k) {
        float4 a  = *(const float4*)&As[k][tm];
        float4 b0 = *(const float4*)&Bs[k][tn4];
        float4 b1 = *(const float4*)&Bs[k][tn4 + 64];
        const float am[4] = {a.x, a.y, a.z, a.w};
#pragma unroll
        for (int mi = 0; mi < 4; ++mi) {
            acc[mi][0][0] += am[mi] * b0.x; acc[mi][0][1] += am[mi] * b0.y;
            acc[mi][0][2] += am[mi] * b0.z; acc[mi][0][3] += am[mi] * b0.w;
            acc[mi][1][0] += am[mi] * b1.x; acc[mi][1][1] += am[mi] * b1.y;
            acc[mi][1][2] += am[mi] * b1.z; acc[mi][1][3] += am[mi] * b1.w;
        }
    }

#pragma unroll
    for (int mi = 0; mi < 4; ++mi) {
        int gm = m0 + tm + mi;
        if (gm < N_NODES) {
            uint2 us, un;
            us.x = pack_bf(acc[mi][0][0], acc[mi][0][1]);
            us.y = pack_bf(acc[mi][0][2], acc[mi][0][3]);
            un.x = pack_bf(acc[mi][1][0], acc[mi][1][1]);
            un.y = pack_bf(acc[mi][1][2], acc[mi][1][3]);
            *(uint2*)&Cself[(size_t)gm * 64 + tn4] = us;
            *(uint2*)&Cn[(size_t)gm * 64 + tn4]    = un;
        }
    }
}

// ---------------- Layer-2 GEMM: A is bf16 [N,64]; outputs bf16 tables ----------------
__global__ __launch_bounds__(256)
void gemm_cat64_bf16(const ushort_t* __restrict__ A,
                     const float* __restrict__ B1,   // [64,32] Ws2
                     const float* __restrict__ B2,   // [64,32] Wn2
                     ushort_t* __restrict__ Cself,   // [N,32] bf16
                     ushort_t* __restrict__ Cn) {    // [N,32] bf16
    __shared__ float As[64][68];
    __shared__ float Bs[64][64];

    for (int i = threadIdx.x; i < 64 * 32; i += 256) {
        int k = i >> 5, j = i & 31;
        Bs[k][j]      = B1[i];
        Bs[k][j + 32] = B2[i];
    }
    const int m0 = blockIdx.x * 64;
    {
        int mloc = threadIdx.x >> 4;          // 0..15
        int k4   = (threadIdx.x & 15) * 4;    // 0..60
#pragma unroll
        for (int it = 0; it < 4; ++it) {
            int m  = mloc + it * 16;
            int gm = m0 + m;
            uint2 a = (gm < N_NODES) ? *(const uint2*)&A[(size_t)gm * 64 + k4]
                                     : make_uint2(0u, 0u);
            As[k4 + 0][m] = bflo(a.x); As[k4 + 1][m] = bfhi(a.x);
            As[k4 + 2][m] = bflo(a.y); As[k4 + 3][m] = bfhi(a.y);
        }
    }
    __syncthreads();

    const int tm  = ((threadIdx.x >> 4) & 3) * 4 + (threadIdx.x >> 6) * 16;  // 0..60
    const int tn4 = (threadIdx.x & 15) * 4;                                   // 0..60

    float acc[4][4];
#pragma unroll
    for (int mi = 0; mi < 4; ++mi)
#pragma unroll
        for (int ni = 0; ni < 4; ++ni) acc[mi][ni] = 0.f;

#pragma unroll 8
    for (int k = 0; k < 64; ++k) {
        float4 a = *(const float4*)&As[k][tm];
        float4 b = *(const float4*)&Bs[k][tn4];
        const float am[4] = {a.x, a.y, a.z, a.w};
#pragma unroll
        for (int mi = 0; mi < 4; ++mi) {
            acc[mi][0] += am[mi] * b.x; acc[mi][1] += am[mi] * b.y;
            acc[mi][2] += am[mi] * b.z; acc[mi][3] += am[mi] * b.w;
        }
    }

#pragma unroll
    for (int mi = 0; mi < 4; ++mi) {
        int gm = m0 + tm + mi;
        if (gm < N_NODES) {
            uint2 u;
            u.x = pack_bf(acc[mi][0], acc[mi][1]);
            u.y = pack_bf(acc[mi][2], acc[mi][3]);
            if (tn4 < 32) *(uint2*)&Cself[(size_t)gm * 32 + tn4] = u;
            else          *(uint2*)&Cn[(size_t)gm * 32 + (tn4 - 32)] = u;
        }
    }
}

// ---------------- Gather mean (bf16 tables, 16 B/lane) + fused epilogue ----------------
// out[v] = act( Tself[v] + mean_{u in N(v)} Tn[u] + bias )
// One wave per node. LPR = F/8 lanes per row (uint4 = 8 bf16 = 16 B each);
// R = 64/LPR rows in flight per tier; 4-deep unroll = 4*R rows outstanding.
template <int F, bool RELU, bool OBF16>
__global__ __launch_bounds__(256)
void gather_epilogue(const ushort_t* __restrict__ Tself,
                     const ushort_t* __restrict__ Tn,
                     const int* __restrict__ row_ptr,
                     const int* __restrict__ csr_src, const float* __restrict__ bias,
                     void* __restrict__ outv) {
    constexpr int LPR = F / 8;
    constexpr int R   = 64 / LPR;
    int v = (blockIdx.x * blockDim.x + threadIdx.x) >> 6;   // node id
    int lane = threadIdx.x & 63;
    int r = lane / LPR;
    int c = lane % LPR;          // handles cols c*8 .. c*8+7
    if (v >= N_NODES) return;
    int start = row_ptr[v];
    int cnt   = row_ptr[v + 1] - start;

    float a[8];
#pragma unroll
    for (int i = 0; i < 8; ++i) a[i] = 0.f;

#define ACC8(u)                                           \
    a[0] += bflo(u.x); a[1] += bfhi(u.x);                 \
    a[2] += bflo(u.y); a[3] += bfhi(u.y);                 \
    a[4] += bflo(u.z); a[5] += bfhi(u.z);                 \
    a[6] += bflo(u.w); a[7] += bfhi(u.w);

    int t = r;
    for (; t + 3 * R < cnt; t += 4 * R) {
        int s0 = csr_src[start + t];
        int s1 = csr_src[start + t + R];
        int s2 = csr_src[start + t + 2 * R];
        int s3 = csr_src[start + t + 3 * R];
        uint4 u0 = *(const uint4*)&Tn[(size_t)s0 * F + c * 8];
        uint4 u1 = *(const uint4*)&Tn[(size_t)s1 * F + c * 8];
        uint4 u2 = *(const uint4*)&Tn[(size_t)s2 * F + c * 8];
        uint4 u3 = *(const uint4*)&Tn[(size_t)s3 * F + c * 8];
        ACC8(u0) ACC8(u1) ACC8(u2) ACC8(u3)
    }
    if (t + R < cnt) {
        int s0 = csr_src[start + t];
        int s1 = csr_src[start + t + R];
        uint4 u0 = *(const uint4*)&Tn[(size_t)s0 * F + c * 8];
        uint4 u1 = *(const uint4*)&Tn[(size_t)s1 * F + c * 8];
        ACC8(u0) ACC8(u1)
        t += 2 * R;
    }
    if (t < cnt) {
        int s = csr_src[start + t];
        uint4 u = *(const uint4*)&Tn[(size_t)s * F + c * 8];
        ACC8(u)
    }
#undef ACC8

#pragma unroll
    for (int off = LPR; off < 64; off <<= 1) {
#pragma unroll
        for (int i = 0; i < 8; ++i) a[i] += __shfl_xor(a[i], off);
    }

    if (r == 0) {
        const float inv = 1.0f / (float)max(cnt, 1);
        uint4 su = *(const uint4*)&Tself[(size_t)v * F + c * 8];
        float4 bA = *(const float4*)&bias[c * 8];
        float4 bB = *(const float4*)&bias[c * 8 + 4];
        float o[8];
        o[0] = bflo(su.x) + a[0] * inv + bA.x;
        o[1] = bfhi(su.x) + a[1] * inv + bA.y;
        o[2] = bflo(su.y) + a[2] * inv + bA.z;
        o[3] = bfhi(su.y) + a[3] * inv + bA.w;
        o[4] = bflo(su.z) + a[4] * inv + bB.x;
        o[5] = bfhi(su.z) + a[5] * inv + bB.y;
        o[6] = bflo(su.w) + a[6] * inv + bB.z;
        o[7] = bfhi(su.w) + a[7] * inv + bB.w;
        if (RELU) {
#pragma unroll
            for (int i = 0; i < 8; ++i) o[i] = fmaxf(o[i], 0.f);
        }
        if (OBF16) {
            ushort_t* out = (ushort_t*)outv;
            uint4 p;
            p.x = pack_bf(o[0], o[1]); p.y = pack_bf(o[2], o[3]);
            p.z = pack_bf(o[4], o[5]); p.w = pack_bf(o[6], o[7]);
            *(uint4*)&out[(size_t)v * F + c * 8] = p;
        } else {
            float* out = (float*)outv;
            *(float4*)&out[(size_t)v * F + c * 8]     = make_float4(o[0], o[1], o[2], o[3]);
            *(float4*)&out[(size_t)v * F + c * 8 + 4] = make_float4(o[4], o[5], o[6], o[7]);
        }
    }
}

extern "C" void kernel_launch(void* const* d_in, const int* in_sizes, int n_in,
                              void* d_out, int out_size, void* d_ws, size_t ws_size,
                              hipStream_t stream) {
    const float* features = (const float*)d_in[0];
    const float* W_self1  = (const float*)d_in[1];
    const float* W_neigh1 = (const float*)d_in[2];
    const float* b1       = (const float*)d_in[3];
    const float* W_self2  = (const float*)d_in[4];
    const float* W_neigh2 = (const float*)d_in[5];
    const float* b2       = (const float*)d_in[6];
    const int*   src      = (const int*)d_in[7];
    const int*   dst      = (const int*)d_in[8];

    // Workspace (all bf16 tables):
    //   Tself1 : N*64 bf16 (6.4 MB)  -- reused as Tself2+Tn2 (N*32 each) after gather1
    //   Tn1    : N*64 bf16 (6.4 MB)
    //   h      : N*64 bf16 (6.4 MB)
    //   row_ptr: N+1; csr_src: E; brec: E; blocktot/blockstart: SCAN_N(+1)
    ushort_t* Tself1 = (ushort_t*)d_ws;
    ushort_t* Tn1    = Tself1 + (size_t)N_NODES * 64;
    ushort_t* h      = Tn1 + (size_t)N_NODES * 64;
    int* row_ptr     = (int*)(h + (size_t)N_NODES * 64);
    int* csr_src     = row_ptr + (N_NODES + 1);
    unsigned int* brec = (unsigned int*)(csr_src + N_EDGES);
    int* blocktot    = (int*)(brec + N_EDGES);
    int* blockstart  = blocktot + SCAN_N;

    ushort_t* Tself2 = Tself1;                       // N*32, reuse (dead after gather1)
    ushort_t* Tn2    = Tself1 + (size_t)N_NODES * 32;

    const int gather_blocks = (N_NODES + 3) / 4;     // 12500 (4 waves/block)

    // ---- Overlapped: layer-1 GEMM + CSR part_count ----
    gemm128_and_count<<<GEMM_BLOCKS + PBLOCKS, 256, 0, stream>>>(
        features, W_self1, W_neigh1, Tself1, Tn1, dst, blocktot);
    // ---- CSR build (by dst), atomic-free partition ----
    part_scan<<<1, 1024, 0, stream>>>(blocktot, blockstart);
    part_write<<<PBLOCKS, 256, 0, stream>>>(src, dst, blockstart, brec);
    bucket_fill<<<NB, 256, 0, stream>>>(blockstart, brec, csr_src, row_ptr);

    // ---- Layer 1 gather + epilogue -> h (bf16) ----
    gather_epilogue<64, true, true><<<gather_blocks, 256, 0, stream>>>(
        Tself1, Tn1, row_ptr, csr_src, b1, h);

    // ---- Layer 2 GEMM (bf16 A) ----
    gemm_cat64_bf16<<<GEMM_BLOCKS, 256, 0, stream>>>(h, W_self2, W_neigh2, Tself2, Tn2);

    // ---- Layer 2 gather + epilogue -> out (fp32) ----
    gather_epilogue<32, false, false><<<gather_blocks, 256, 0, stream>>>(
        Tself2, Tn2, row_ptr, csr_src, b2, d_out);
}